// Round 1
// baseline (578.907 us; speedup 1.0000x reference)
//
#include <hip/hip_runtime.h>
#include <hip/hip_bf16.h>

#define S 512
#define D 384
#define H 8
#define KD 48
#define NROW 1024            // B*S
#define F 147456             // D*D
#define KSPLIT 16
#define KSPAN (F / KSPLIT)   // 9216
#define BK 64

typedef __attribute__((ext_vector_type(8))) short short8;
typedef __attribute__((ext_vector_type(4))) float f32x4;

__device__ inline unsigned short f2bf(float x) {
  unsigned int u = __builtin_bit_cast(unsigned int, x);
  u += 0x7FFFu + ((u >> 16) & 1u);   // RTNE
  return (unsigned short)(u >> 16);
}

// ---------------------------------------------------------------------------
// prep: Wall[384][1152] = [ Wq*temp | Wk | Wv@T ]
// ---------------------------------------------------------------------------
__global__ __launch_bounds__(256) void prep_wall(
    const float* __restrict__ Wq, const float* __restrict__ Wk,
    const float* __restrict__ Wv, const float* __restrict__ T,
    const float* __restrict__ temp, float* __restrict__ Wall) {
  int idx = blockIdx.x * 256 + threadIdx.x;   // < 442368
  int d = idx / 1152, c = idx - (idx / 1152) * 1152;
  float v;
  if (c < 384) {
    v = Wq[d * 384 + c] * temp[c / 48];
  } else if (c < 768) {
    v = Wk[d * 384 + (c - 384)];
  } else {
    int n = c - 768;
    int h = n / 48, nn = n - h * 48;
    float s = 0.f;
    for (int m = 0; m < 48; ++m) s += Wv[d * 384 + h * 48 + m] * T[m * 48 + nn];
    v = s;
  }
  Wall[idx] = v;
}

// ---------------------------------------------------------------------------
// generic fp32 GEMM, 64x64 tile, 256 threads, 4x4 microtile. M,N %64==0, K %16==0
// ---------------------------------------------------------------------------
__global__ __launch_bounds__(256) void gemm64(
    const float* __restrict__ A, const float* __restrict__ B,
    float* __restrict__ Cout, int M, int N, int K) {
  __shared__ float As[64][17];
  __shared__ float Bs[16][65];
  int t = threadIdx.x;
  int tx = t & 15, ty = t >> 4;
  int m0 = blockIdx.y * 64, n0 = blockIdx.x * 64;
  float acc[4][4] = {};
  for (int k0 = 0; k0 < K; k0 += 16) {
    __syncthreads();
#pragma unroll
    for (int p = 0; p < 4; ++p) {
      int idx = t + 256 * p;
      int r = idx >> 4, c = idx & 15;
      As[r][c] = A[(size_t)(m0 + r) * K + k0 + c];
    }
#pragma unroll
    for (int p = 0; p < 4; ++p) {
      int idx = t + 256 * p;
      int r = idx >> 6, c = idx & 63;
      Bs[r][c] = B[(size_t)(k0 + r) * N + n0 + c];
    }
    __syncthreads();
#pragma unroll
    for (int kk = 0; kk < 16; ++kk) {
      float a[4], b[4];
#pragma unroll
      for (int i = 0; i < 4; ++i) a[i] = As[ty * 4 + i][kk];
#pragma unroll
      for (int j = 0; j < 4; ++j) b[j] = Bs[kk][tx * 4 + j];
#pragma unroll
      for (int i = 0; i < 4; ++i)
#pragma unroll
        for (int j = 0; j < 4; ++j) acc[i][j] += a[i] * b[j];
    }
  }
#pragma unroll
  for (int i = 0; i < 4; ++i)
#pragma unroll
    for (int j = 0; j < 4; ++j)
      Cout[(size_t)(m0 + ty * 4 + i) * N + n0 + tx * 4 + j] = acc[i][j];
}

// ---------------------------------------------------------------------------
// gate[b,s,h] = sigmoid(curvature[b,s,:] . gate_kernel[:,h])
// ---------------------------------------------------------------------------
__global__ __launch_bounds__(256) void gate_k(
    const float* __restrict__ curv, const float* __restrict__ gk,
    float* __restrict__ gate) {
  int g = blockIdx.x * 256 + threadIdx.x;   // < 8192
  int sg = g >> 3, h = g & 7;
  const float* crow = curv + (size_t)sg * 384;
  float dot = 0.f;
  for (int d = 0; d < 384; ++d) dot += crow[d] * gk[d * 8 + h];
  gate[g] = 1.0f / (1.0f + __expf(-dot));
}

// ---------------------------------------------------------------------------
// gram: C[b][i][j] += sum_k X[b,i,k]*X[b,j,k]  (bf16 MFMA, split-K, atomics)
// grid = 512: blk&7 keeps one K-split per XCD for L2 reuse.
// ---------------------------------------------------------------------------
__global__ __launch_bounds__(256) void gram_k(const float* __restrict__ X,
                                              float* __restrict__ C) {
  int blk = blockIdx.x;
  int split = (blk & 7) | ((blk >> 8) << 3);
  int inner = (blk >> 3) & 31;
  int batch = inner >> 4;
  int tile = inner & 15;
  int ti = tile >> 2, tj = tile & 3;
  const float* Xb = X + (size_t)batch * S * F;
  int i0 = ti * 128, j0 = tj * 128;
  int k0b = split * KSPAN;

  __shared__ short lds[2 * 128 * 64];   // A | B bf16 panels, XOR-swizzled
  char* ldsA = (char*)lds;
  char* ldsB = (char*)lds + 128 * 64 * 2;

  int t = threadIdx.x;
  int lane = t & 63;
  int wave = t >> 6;
  int wm = wave >> 1, wn = wave & 1;

  f32x4 acc[4][4];
#pragma unroll
  for (int i = 0; i < 4; ++i)
#pragma unroll
    for (int j = 0; j < 4; ++j) acc[i][j] = (f32x4){0.f, 0.f, 0.f, 0.f};

  for (int ks = 0; ks < KSPAN / BK; ++ks) {
    int k0 = k0b + ks * BK;
    __syncthreads();
#pragma unroll
    for (int p = 0; p < 8; ++p) {
      int idx = t + 256 * p;           // 2048 float4 = 128 rows x 16
      int row = idx >> 4;
      int c4 = idx & 15;
      float4 v = *(const float4*)(Xb + (size_t)(i0 + row) * F + k0 + c4 * 4);
      ushort4 hv;
      hv.x = f2bf(v.x); hv.y = f2bf(v.y); hv.z = f2bf(v.z); hv.w = f2bf(v.w);
      int a = (row * 128 + c4 * 8) ^ ((row & 7) << 4);
      *(ushort4*)(ldsA + a) = hv;
    }
    if (ti != tj) {
#pragma unroll
      for (int p = 0; p < 8; ++p) {
        int idx = t + 256 * p;
        int row = idx >> 4;
        int c4 = idx & 15;
        float4 v = *(const float4*)(Xb + (size_t)(j0 + row) * F + k0 + c4 * 4);
        ushort4 hv;
        hv.x = f2bf(v.x); hv.y = f2bf(v.y); hv.z = f2bf(v.z); hv.w = f2bf(v.w);
        int a = (row * 128 + c4 * 8) ^ ((row & 7) << 4);
        *(ushort4*)(ldsB + a) = hv;
      }
    }
    __syncthreads();
    const char* Bp = (ti == tj) ? (const char*)ldsA : (const char*)ldsB;
#pragma unroll
    for (int ksub = 0; ksub < 2; ++ksub) {
      short8 af[4], bf[4];
      int kb = ksub * 64 + (lane >> 4) * 16;   // byte offset of k within row
#pragma unroll
      for (int mt = 0; mt < 4; ++mt) {
        int row = wm * 64 + mt * 16 + (lane & 15);
        af[mt] = *(const short8*)(ldsA + ((row * 128 + kb) ^ ((row & 7) << 4)));
      }
#pragma unroll
      for (int nt = 0; nt < 4; ++nt) {
        int row = wn * 64 + nt * 16 + (lane & 15);
        bf[nt] = *(const short8*)(Bp + ((row * 128 + kb) ^ ((row & 7) << 4)));
      }
#pragma unroll
      for (int mt = 0; mt < 4; ++mt)
#pragma unroll
        for (int nt = 0; nt < 4; ++nt)
          acc[mt][nt] = __builtin_amdgcn_mfma_f32_16x16x32_bf16(
              af[mt], bf[nt], acc[mt][nt], 0, 0, 0);
    }
  }
  // D layout: col = lane&15, row = (lane>>4)*4 + reg  (C symmetric => robust)
  int cn = lane & 15;
  int r0 = (lane >> 4) * 4;
#pragma unroll
  for (int mt = 0; mt < 4; ++mt)
#pragma unroll
    for (int nt = 0; nt < 4; ++nt)
#pragma unroll
      for (int r = 0; r < 4; ++r) {
        int i = i0 + wm * 64 + mt * 16 + r0 + r;
        int j = j0 + wn * 64 + nt * 16 + cn;
        atomicAdd(&C[((size_t)batch * S + i) * S + j], acc[mt][nt][r]);
      }
}

// ---------------------------------------------------------------------------
// scores + softmax: attn[b,h,i,j] = softmax_j( (q'_i.k_j + 0.1*temp_h*hol_ij) * gate[b,j,h] )
// hol_ij = 2*C_ij/f - C_ii/f - C_jj/f.  block = (b,h, 64-row chunk), 256 thr
// ---------------------------------------------------------------------------
__global__ __launch_bounds__(256) void scores_softmax(
    const float* __restrict__ qkv, const float* __restrict__ gate,
    const float* __restrict__ C, const float* __restrict__ temp,
    float* __restrict__ attn) {
  int bid = blockIdx.x;
  int b = bid >> 6;
  int rem = bid & 63;
  int h = rem >> 3;
  int ic = rem & 7;
  int i0 = ic * 64;

  __shared__ float kh[512][49];
  __shared__ float qs[64][48];
  __shared__ float gs[512];
  __shared__ float sqv[512];
  __shared__ float red[4];

  int t = threadIdx.x;
  const float invF = 1.0f / 147456.0f;
  float ch = 0.1f * temp[h];

  for (int idx = t; idx < 512 * 48; idx += 256) {
    int s = idx / 48, kd = idx - (idx / 48) * 48;
    kh[s][kd] = qkv[(size_t)(b * S + s) * 1152 + 384 + h * 48 + kd];
  }
  for (int idx = t; idx < 64 * 48; idx += 256) {
    int r = idx / 48, kd = idx - (idx / 48) * 48;
    qs[r][kd] = qkv[(size_t)(b * S + i0 + r) * 1152 + h * 48 + kd];
  }
  for (int j = t; j < 512; j += 256) {
    gs[j] = gate[(b * S + j) * 8 + h];
    sqv[j] = C[((size_t)b * S + j) * S + j] * invF;
  }
  __syncthreads();

  int lane = t & 63;
  int wv = t >> 6;
  for (int r = 0; r < 64; ++r) {
    int i = i0 + r;
    const float* Crow = C + ((size_t)b * S + i) * S;
    float sqi = sqv[i];
    float s0, s1;
    {
      int j = t;
      float dot = 0.f;
#pragma unroll
      for (int kd = 0; kd < 48; ++kd) dot += qs[r][kd] * kh[j][kd];
      s0 = (dot + ch * (2.0f * Crow[j] * invF - sqi - sqv[j])) * gs[j];
    }
    {
      int j = t + 256;
      float dot = 0.f;
#pragma unroll
      for (int kd = 0; kd < 48; ++kd) dot += qs[r][kd] * kh[j][kd];
      s1 = (dot + ch * (2.0f * Crow[j] * invF - sqi - sqv[j])) * gs[j];
    }
    float m = fmaxf(s0, s1);
#pragma unroll
    for (int off = 32; off; off >>= 1) m = fmaxf(m, __shfl_xor(m, off));
    __syncthreads();
    if (lane == 0) red[wv] = m;
    __syncthreads();
    m = fmaxf(fmaxf(red[0], red[1]), fmaxf(red[2], red[3]));
    float e0 = __expf(s0 - m), e1 = __expf(s1 - m);
    float sm = e0 + e1;
#pragma unroll
    for (int off = 32; off; off >>= 1) sm += __shfl_xor(sm, off);
    __syncthreads();
    if (lane == 0) red[wv] = sm;
    __syncthreads();
    float inv = 1.0f / (red[0] + red[1] + red[2] + red[3]);
    float* arow = attn + (((size_t)(b * 8 + h)) * S + i) * S;
    arow[t] = e0 * inv;
    arow[t + 256] = e1 * inv;
  }
}

// ---------------------------------------------------------------------------
// PV: ctx[b,i,h,m] = sum_j attn[b,h,i,j] * v_t[b,j,h,m]. block=(b,h,64 rows)
// ---------------------------------------------------------------------------
__global__ __launch_bounds__(256) void pv_k(const float* __restrict__ attn,
                                            const float* __restrict__ qkv,
                                            float* __restrict__ ctx) {
  int bid = blockIdx.x;
  int b = bid >> 6;
  int rem = bid & 63;
  int h = rem >> 3;
  int ic = rem & 7;
  int i0 = ic * 64;

  __shared__ float vts[64][48];
  __shared__ float ats[64][65];
  int t = threadIdx.x;
  int tx = t & 15, ty = t >> 4;
  int r0 = ty * 4, m0 = tx * 3;
  float acc[4][3] = {};
  for (int jc = 0; jc < 8; ++jc) {
    __syncthreads();
    for (int idx = t; idx < 3072; idx += 256) {
      int jr = idx / 48, m = idx - (idx / 48) * 48;
      vts[jr][m] = qkv[(size_t)(b * S + jc * 64 + jr) * 1152 + 768 + h * 48 + m];
    }
    for (int idx = t; idx < 4096; idx += 256) {
      int r = idx >> 6, j = idx & 63;
      ats[r][j] = attn[(((size_t)(b * 8 + h)) * S + i0 + r) * S + jc * 64 + j];
    }
    __syncthreads();
#pragma unroll 4
    for (int jj = 0; jj < 64; ++jj) {
      float bv0 = vts[jj][m0], bv1 = vts[jj][m0 + 1], bv2 = vts[jj][m0 + 2];
#pragma unroll
      for (int ii = 0; ii < 4; ++ii) {
        float av = ats[r0 + ii][jj];
        acc[ii][0] += av * bv0;
        acc[ii][1] += av * bv1;
        acc[ii][2] += av * bv2;
      }
    }
  }
#pragma unroll
  for (int ii = 0; ii < 4; ++ii)
#pragma unroll
    for (int jm = 0; jm < 3; ++jm)
      ctx[(size_t)(b * S + i0 + r0 + ii) * 384 + h * 48 + m0 + jm] = acc[ii][jm];
}

// ---------------------------------------------------------------------------
extern "C" void kernel_launch(void* const* d_in, const int* in_sizes, int n_in,
                              void* d_out, int out_size, void* d_ws, size_t ws_size,
                              hipStream_t stream) {
  const float* emb  = (const float*)d_in[0];
  const float* curv = (const float*)d_in[1];
  const float* conn = (const float*)d_in[2];
  const float* Wq   = (const float*)d_in[3];
  const float* Wk   = (const float*)d_in[4];
  const float* Wv   = (const float*)d_in[5];
  const float* Wo   = (const float*)d_in[6];
  const float* gk   = (const float*)d_in[7];
  const float* T    = (const float*)d_in[8];
  const float* temp = (const float*)d_in[9];

  float* ws   = (float*)d_ws;
  float* C    = ws;                    // 524288          (2MB)
  float* qkv  = ws + 524288;           // 1179648: [1024][ q' | k | v_t ]
  float* gate = ws + 1703936;          // 8192
  float* Wall = ws + 1712128;          // 442368
  float* attn = ws + 2154496;          // 4194304         (16MB)
  float* ctx  = ws + 6348800;          // 393216   -> total ~27MB

  hipMemsetAsync(C, 0, 524288 * sizeof(float), stream);
  prep_wall<<<1728, 256, 0, stream>>>(Wq, Wk, Wv, T, temp, Wall);
  gemm64<<<dim3(18, 16), 256, 0, stream>>>(emb, Wall, qkv, 1024, 1152, 384);
  gate_k<<<32, 256, 0, stream>>>(curv, gk, gate);
  gram_k<<<512, 256, 0, stream>>>(conn, C);
  scores_softmax<<<128, 256, 0, stream>>>(qkv, gate, C, temp, attn);
  pv_k<<<128, 256, 0, stream>>>(attn, qkv, ctx);
  gemm64<<<dim3(6, 16), 256, 0, stream>>>(ctx, Wo, (float*)d_out, 1024, 384, 384);
}

// Round 2
// 497.501 us; speedup vs baseline: 1.1636x; 1.1636x over previous
//
#include <hip/hip_runtime.h>
#include <hip/hip_bf16.h>

#define S 512
#define D 384
#define H 8
#define F 147456             // D*D
#define GSPLIT 32
#define GSPAN (F / GSPLIT)   // 4608
#define GITER (GSPAN / 64)   // 72

typedef __attribute__((ext_vector_type(8))) short short8;
typedef __attribute__((ext_vector_type(8))) unsigned short u16x8;
typedef __attribute__((ext_vector_type(4))) float f32x4;

__device__ inline unsigned short bfr(float x) {
  return __builtin_bit_cast(unsigned short, __float2bfloat16(x));
}

__device__ inline void stash(void* dst, float4 a, float4 b) {
  u16x8 h;
  h[0] = bfr(a.x); h[1] = bfr(a.y); h[2] = bfr(a.z); h[3] = bfr(a.w);
  h[4] = bfr(b.x); h[5] = bfr(b.y); h[6] = bfr(b.z); h[7] = bfr(b.w);
  *(u16x8*)dst = h;
}

// ---------------------------------------------------------------------------
// prep: Wall[384][1152] = [ Wq*temp | Wk | Wv@T ]
// ---------------------------------------------------------------------------
__global__ __launch_bounds__(256) void prep_wall(
    const float* __restrict__ Wq, const float* __restrict__ Wk,
    const float* __restrict__ Wv, const float* __restrict__ T,
    const float* __restrict__ temp, float* __restrict__ Wall) {
  int idx = blockIdx.x * 256 + threadIdx.x;   // < 442368
  int d = idx / 1152, c = idx - (idx / 1152) * 1152;
  float v;
  if (c < 384) {
    v = Wq[d * 384 + c] * temp[c / 48];
  } else if (c < 768) {
    v = Wk[d * 384 + (c - 384)];
  } else {
    int n = c - 768;
    int h = n / 48, nn = n - h * 48;
    float s = 0.f;
    for (int m = 0; m < 48; ++m) s += Wv[d * 384 + h * 48 + m] * T[m * 48 + nn];
    v = s;
  }
  Wall[idx] = v;
}

// ---------------------------------------------------------------------------
// generic fp32 GEMM, 64x64 tile, 256 threads, 4x4 microtile. M,N %64==0, K %16==0
// ---------------------------------------------------------------------------
__global__ __launch_bounds__(256) void gemm64(
    const float* __restrict__ A, const float* __restrict__ B,
    float* __restrict__ Cout, int M, int N, int K) {
  __shared__ float As[64][17];
  __shared__ float Bs[16][65];
  int t = threadIdx.x;
  int tx = t & 15, ty = t >> 4;
  int m0 = blockIdx.y * 64, n0 = blockIdx.x * 64;
  float acc[4][4] = {};
  for (int k0 = 0; k0 < K; k0 += 16) {
    __syncthreads();
#pragma unroll
    for (int p = 0; p < 4; ++p) {
      int idx = t + 256 * p;
      int r = idx >> 4, c = idx & 15;
      As[r][c] = A[(size_t)(m0 + r) * K + k0 + c];
    }
#pragma unroll
    for (int p = 0; p < 4; ++p) {
      int idx = t + 256 * p;
      int r = idx >> 6, c = idx & 63;
      Bs[r][c] = B[(size_t)(k0 + r) * N + n0 + c];
    }
    __syncthreads();
#pragma unroll
    for (int kk = 0; kk < 16; ++kk) {
      float a[4], b[4];
#pragma unroll
      for (int i = 0; i < 4; ++i) a[i] = As[ty * 4 + i][kk];
#pragma unroll
      for (int j = 0; j < 4; ++j) b[j] = Bs[kk][tx * 4 + j];
#pragma unroll
      for (int i = 0; i < 4; ++i)
#pragma unroll
        for (int j = 0; j < 4; ++j) acc[i][j] += a[i] * b[j];
    }
  }
#pragma unroll
  for (int i = 0; i < 4; ++i)
#pragma unroll
    for (int j = 0; j < 4; ++j)
      Cout[(size_t)(m0 + ty * 4 + i) * N + n0 + tx * 4 + j] = acc[i][j];
}

// ---------------------------------------------------------------------------
// gate[b,s,h] = sigmoid(curvature[b,s,:] . gate_kernel[:,h])
// ---------------------------------------------------------------------------
__global__ __launch_bounds__(256) void gate_k(
    const float* __restrict__ curv, const float* __restrict__ gk,
    float* __restrict__ gate) {
  int g = blockIdx.x * 256 + threadIdx.x;   // < 8192
  int sg = g >> 3, h = g & 7;
  const float* crow = curv + (size_t)sg * 384;
  float dot = 0.f;
  for (int d = 0; d < 384; ++d) dot += crow[d] * gk[d * 8 + h];
  gate[g] = 1.0f / (1.0f + __expf(-dot));
}

// ---------------------------------------------------------------------------
// gram: C[b][i][j] += sum_k X[b,i,k]*X[b,j,k]
// Triangular 256^2 tiles (t0=(0,0), t1=(0,1), t2=(1,1)), split-K=32, atomics.
// 512 thr = 8 waves (2m x 4n), wave tile 128x64, bf16 MFMA 16x16x32.
// LDS double-buffered 2 x (A 32KB | B 32KB) = 128KB; T14 reg prefetch.
// blockIdx -> (b,split,tile) via inverse-XCD map so the 3 tiles of one
// (b,split) land on one XCD (L2 catches the 2x panel reuse).
// ---------------------------------------------------------------------------
__global__ __launch_bounds__(512) void gram_k(const float* __restrict__ X,
                                              float* __restrict__ C) {
  int Bh = blockIdx.x;                 // 0..191
  int L = (Bh & 7) * 24 + (Bh >> 3);   // logical: 24 consecutive per XCD
  int tile = L % 3;
  int grp = L / 3;
  int b = grp & 1;
  int split = grp >> 1;                // 0..31
  int ti = (tile == 2) ? 1 : 0;
  int tj = (tile == 0) ? 0 : 1;
  bool diag = (ti == tj);
  const float* Xb = X + (size_t)b * S * F;
  int i0 = ti * 256, j0 = tj * 256;
  int k0b = split * GSPAN;

  __shared__ short lds[65536];         // 128KB: [2 buf][A 32KB | B 32KB]
  char* ldsc = (char*)lds;

  int t = threadIdx.x;
  int lane = t & 63, wave = t >> 6;
  int wm = wave >> 2, wn = wave & 3;   // 2 x 4 wave grid

  f32x4 acc[8][4];
#pragma unroll
  for (int mt = 0; mt < 8; ++mt)
#pragma unroll
    for (int nt = 0; nt < 4; ++nt) acc[mt][nt] = (f32x4){0.f, 0.f, 0.f, 0.f};

  // prologue: stage chunk 0 into buf 0
  for (int h = 0; h < (diag ? 1 : 2); ++h) {
    int rbase = h ? j0 : i0;
#pragma unroll
    for (int g = 0; g < 4; ++g) {
      int pg = g * 512 + t;            // 0..2047 within panel
      int row = pg >> 3, kg = pg & 7;
      const float* src = Xb + (size_t)(rbase + row) * F + k0b + kg * 8;
      float4 v0 = ((const float4*)src)[0];
      float4 v1 = ((const float4*)src)[1];
      stash(ldsc + h * 32768 + row * 128 + ((kg * 16) ^ ((row & 7) << 4)), v0, v1);
    }
  }
  __syncthreads();

  for (int ks = 0; ks < GITER; ++ks) {
    int cur = ks & 1;
    const char* pA = ldsc + cur * 65536;
    const char* pB = diag ? pA : (pA + 32768);
    char* wb = ldsc + (cur ^ 1) * 65536;
    bool pf = (ks + 1 < GITER);
    int k0n = k0b + (ks + 1) * 64;

    float4 ga[8];
    if (pf) {
#pragma unroll
      for (int g = 0; g < 4; ++g) {
        int pg = g * 512 + t;
        int row = pg >> 3, kg = pg & 7;
        const float* src = Xb + (size_t)(i0 + row) * F + k0n + kg * 8;
        ga[2 * g]     = ((const float4*)src)[0];
        ga[2 * g + 1] = ((const float4*)src)[1];
      }
    }

    // ksub 0
    {
      short8 af[8], bfv[4];
      int kb = (lane >> 4) * 16;
#pragma unroll
      for (int mt = 0; mt < 8; ++mt) {
        int row = wm * 128 + mt * 16 + (lane & 15);
        af[mt] = *(const short8*)(pA + row * 128 + (kb ^ ((row & 7) << 4)));
      }
#pragma unroll
      for (int nt = 0; nt < 4; ++nt) {
        int row = wn * 64 + nt * 16 + (lane & 15);
        bfv[nt] = *(const short8*)(pB + row * 128 + (kb ^ ((row & 7) << 4)));
      }
#pragma unroll
      for (int mt = 0; mt < 8; ++mt)
#pragma unroll
        for (int nt = 0; nt < 4; ++nt)
          acc[mt][nt] = __builtin_amdgcn_mfma_f32_16x16x32_bf16(
              af[mt], bfv[nt], acc[mt][nt], 0, 0, 0);
    }

    if (pf) {
#pragma unroll
      for (int g = 0; g < 4; ++g) {
        int pg = g * 512 + t;
        int row = pg >> 3, kg = pg & 7;
        stash(wb + row * 128 + ((kg * 16) ^ ((row & 7) << 4)), ga[2 * g], ga[2 * g + 1]);
      }
      if (!diag) {
#pragma unroll
        for (int g = 0; g < 4; ++g) {
          int pg = g * 512 + t;
          int row = pg >> 3, kg = pg & 7;
          const float* src = Xb + (size_t)(j0 + row) * F + k0n + kg * 8;
          ga[2 * g]     = ((const float4*)src)[0];
          ga[2 * g + 1] = ((const float4*)src)[1];
        }
      }
    }

    // ksub 1
    {
      short8 af[8], bfv[4];
      int kb = 64 + (lane >> 4) * 16;
#pragma unroll
      for (int mt = 0; mt < 8; ++mt) {
        int row = wm * 128 + mt * 16 + (lane & 15);
        af[mt] = *(const short8*)(pA + row * 128 + (kb ^ ((row & 7) << 4)));
      }
#pragma unroll
      for (int nt = 0; nt < 4; ++nt) {
        int row = wn * 64 + nt * 16 + (lane & 15);
        bfv[nt] = *(const short8*)(pB + row * 128 + (kb ^ ((row & 7) << 4)));
      }
#pragma unroll
      for (int mt = 0; mt < 8; ++mt)
#pragma unroll
        for (int nt = 0; nt < 4; ++nt)
          acc[mt][nt] = __builtin_amdgcn_mfma_f32_16x16x32_bf16(
              af[mt], bfv[nt], acc[mt][nt], 0, 0, 0);
    }

    if (pf && !diag) {
#pragma unroll
      for (int g = 0; g < 4; ++g) {
        int pg = g * 512 + t;
        int row = pg >> 3, kg = pg & 7;
        stash(wb + 32768 + row * 128 + ((kg * 16) ^ ((row & 7) << 4)),
              ga[2 * g], ga[2 * g + 1]);
      }
    }
    __syncthreads();
  }

  // epilogue: C/D layout col=lane&15, row=(lane>>4)*4+reg (C symmetric => robust)
  int cn = lane & 15, r0 = (lane >> 4) * 4;
#pragma unroll
  for (int mt = 0; mt < 8; ++mt)
#pragma unroll
    for (int nt = 0; nt < 4; ++nt)
#pragma unroll
      for (int r = 0; r < 4; ++r) {
        int i = i0 + wm * 128 + mt * 16 + r0 + r;
        int j = j0 + wn * 64 + nt * 16 + cn;
        atomicAdd(&C[((size_t)b * S + i) * S + j], acc[mt][nt][r]);
      }
}

// ---------------------------------------------------------------------------
// mirror: C[b][256+i][j] = C[b][j][256+i]  (fill the (1,0) quadrant)
// ---------------------------------------------------------------------------
__global__ __launch_bounds__(256) void mirror_k(float* __restrict__ C) {
  int b = blockIdx.x >> 4;
  int ti = (blockIdx.x >> 2) & 3, tj = blockIdx.x & 3;
  __shared__ float tile[64][65];
  int t = threadIdx.x;
  int tx = t & 63, ty = t >> 6;
#pragma unroll
  for (int r = 0; r < 64; r += 4) {
    int j = tj * 64 + r + ty;
    tile[r + ty][tx] = C[((size_t)b * 512 + j) * 512 + 256 + ti * 64 + tx];
  }
  __syncthreads();
#pragma unroll
  for (int r = 0; r < 64; r += 4) {
    int i = 256 + ti * 64 + r + ty;
    C[((size_t)b * 512 + i) * 512 + tj * 64 + tx] = tile[tx][r + ty];
  }
}

// ---------------------------------------------------------------------------
// scores + softmax, wave-per-row (no per-row __syncthreads):
// attn[b,h,i,j] = softmax_j( (q'_i.k_j + 0.1*temp_h*hol_ij) * gate[b,j,h] )
// ---------------------------------------------------------------------------
__global__ __launch_bounds__(256) void scores_softmax(
    const float* __restrict__ qkv, const float* __restrict__ gate,
    const float* __restrict__ C, const float* __restrict__ temp,
    float* __restrict__ attn) {
  int bid = blockIdx.x;
  int b = bid >> 6;
  int rem = bid & 63;
  int h = rem >> 3;
  int ic = rem & 7;
  int i0 = ic * 64;

  __shared__ float kh[512][49];
  __shared__ float qs[64][48];
  __shared__ float gs[512];
  __shared__ float sqv[512];

  int t = threadIdx.x;
  const float invF = 1.0f / 147456.0f;
  float ch = 0.1f * temp[h];

  for (int idx = t; idx < 512 * 48; idx += 256) {
    int s = idx / 48, kd = idx - (idx / 48) * 48;
    kh[s][kd] = qkv[(size_t)(b * S + s) * 1152 + 384 + h * 48 + kd];
  }
  for (int idx = t; idx < 64 * 48; idx += 256) {
    int r = idx / 48, kd = idx - (idx / 48) * 48;
    qs[r][kd] = qkv[(size_t)(b * S + i0 + r) * 1152 + h * 48 + kd];
  }
  for (int j = t; j < 512; j += 256) {
    gs[j] = gate[(b * S + j) * 8 + h];
    sqv[j] = C[((size_t)b * S + j) * S + j] * invF;
  }
  __syncthreads();

  int lane = t & 63, wv = t >> 6;
  for (int rr = 0; rr < 16; ++rr) {
    int r = wv * 16 + rr;
    int i = i0 + r;
    const float* Crow = C + ((size_t)b * S + i) * S;
    float sqi = sqv[i];
    float sc[8];
#pragma unroll
    for (int jj = 0; jj < 8; ++jj) {
      int j = jj * 64 + lane;
      float dot = 0.f;
#pragma unroll
      for (int kd = 0; kd < 48; ++kd) dot += qs[r][kd] * kh[j][kd];
      sc[jj] = (dot + ch * (2.0f * Crow[j] * invF - sqi - sqv[j])) * gs[j];
    }
    float m = sc[0];
#pragma unroll
    for (int jj = 1; jj < 8; ++jj) m = fmaxf(m, sc[jj]);
#pragma unroll
    for (int off = 32; off; off >>= 1) m = fmaxf(m, __shfl_xor(m, off));
    float e[8];
    float sum = 0.f;
#pragma unroll
    for (int jj = 0; jj < 8; ++jj) { e[jj] = __expf(sc[jj] - m); sum += e[jj]; }
#pragma unroll
    for (int off = 32; off; off >>= 1) sum += __shfl_xor(sum, off);
    float inv = 1.0f / sum;
    float* arow = attn + (((size_t)(b * 8 + h)) * S + i) * S;
#pragma unroll
    for (int jj = 0; jj < 8; ++jj) arow[jj * 64 + lane] = e[jj] * inv;
  }
}

// ---------------------------------------------------------------------------
// PV: ctx[b,i,h,m] = sum_j attn[b,h,i,j] * v_t[b,j,h,m]. block=(b,h,64 rows)
// ---------------------------------------------------------------------------
__global__ __launch_bounds__(256) void pv_k(const float* __restrict__ attn,
                                            const float* __restrict__ qkv,
                                            float* __restrict__ ctx) {
  int bid = blockIdx.x;
  int b = bid >> 6;
  int rem = bid & 63;
  int h = rem >> 3;
  int ic = rem & 7;
  int i0 = ic * 64;

  __shared__ float vts[64][48];
  __shared__ float ats[64][65];
  int t = threadIdx.x;
  int tx = t & 15, ty = t >> 4;
  int r0 = ty * 4, m0 = tx * 3;
  float acc[4][3] = {};
  for (int jc = 0; jc < 8; ++jc) {
    __syncthreads();
    for (int idx = t; idx < 3072; idx += 256) {
      int jr = idx / 48, m = idx - (idx / 48) * 48;
      vts[jr][m] = qkv[(size_t)(b * S + jc * 64 + jr) * 1152 + 768 + h * 48 + m];
    }
    for (int idx = t; idx < 4096; idx += 256) {
      int r = idx >> 6, j = idx & 63;
      ats[r][j] = attn[(((size_t)(b * 8 + h)) * S + i0 + r) * S + jc * 64 + j];
    }
    __syncthreads();
#pragma unroll 4
    for (int jj = 0; jj < 64; ++jj) {
      float bv0 = vts[jj][m0], bv1 = vts[jj][m0 + 1], bv2 = vts[jj][m0 + 2];
#pragma unroll
      for (int ii = 0; ii < 4; ++ii) {
        float av = ats[r0 + ii][jj];
        acc[ii][0] += av * bv0;
        acc[ii][1] += av * bv1;
        acc[ii][2] += av * bv2;
      }
    }
  }
#pragma unroll
  for (int ii = 0; ii < 4; ++ii)
#pragma unroll
    for (int jm = 0; jm < 3; ++jm)
      ctx[(size_t)(b * S + i0 + r0 + ii) * 384 + h * 48 + m0 + jm] = acc[ii][jm];
}

// ---------------------------------------------------------------------------
extern "C" void kernel_launch(void* const* d_in, const int* in_sizes, int n_in,
                              void* d_out, int out_size, void* d_ws, size_t ws_size,
                              hipStream_t stream) {
  const float* emb  = (const float*)d_in[0];
  const float* curv = (const float*)d_in[1];
  const float* conn = (const float*)d_in[2];
  const float* Wq   = (const float*)d_in[3];
  const float* Wk   = (const float*)d_in[4];
  const float* Wv   = (const float*)d_in[5];
  const float* Wo   = (const float*)d_in[6];
  const float* gk   = (const float*)d_in[7];
  const float* T    = (const float*)d_in[8];
  const float* temp = (const float*)d_in[9];

  float* ws   = (float*)d_ws;
  float* C    = ws;                    // 524288          (2MB)
  float* qkv  = ws + 524288;           // 1179648: [1024][ q' | k | v_t ]
  float* gate = ws + 1703936;          // 8192
  float* Wall = ws + 1712128;          // 442368
  float* attn = ws + 2154496;          // 4194304         (16MB)
  float* ctx  = ws + 6348800;          // 393216   -> total ~27MB

  hipMemsetAsync(C, 0, 524288 * sizeof(float), stream);
  prep_wall<<<1728, 256, 0, stream>>>(Wq, Wk, Wv, T, temp, Wall);
  gemm64<<<dim3(18, 16), 256, 0, stream>>>(emb, Wall, qkv, 1024, 1152, 384);
  gate_k<<<32, 256, 0, stream>>>(curv, gk, gate);
  gram_k<<<192, 512, 0, stream>>>(conn, C);
  mirror_k<<<32, 256, 0, stream>>>(C);
  scores_softmax<<<128, 256, 0, stream>>>(qkv, gate, C, temp, attn);
  pv_k<<<128, 256, 0, stream>>>(attn, qkv, ctx);
  gemm64<<<dim3(6, 16), 256, 0, stream>>>(ctx, Wo, (float*)d_out, 1024, 384, 384);
}

// Round 3
// 474.309 us; speedup vs baseline: 1.2205x; 1.0489x over previous
//
#include <hip/hip_runtime.h>
#include <hip/hip_bf16.h>

#define S 512
#define D 384
#define H 8
#define F 147456             // D*D
#define GSPLIT 24
#define GSPAN (F / GSPLIT)   // 6144
#define GITER (GSPAN / 64)   // 96

typedef __attribute__((ext_vector_type(8))) short short8;
typedef __attribute__((ext_vector_type(8))) unsigned short u16x8;
typedef __attribute__((ext_vector_type(4))) float f32x4;

__device__ inline unsigned short bfr(float x) {
  return __builtin_bit_cast(unsigned short, __float2bfloat16(x));
}

__device__ inline void stash(void* dst, float4 a, float4 b) {
  u16x8 h;
  h[0] = bfr(a.x); h[1] = bfr(a.y); h[2] = bfr(a.z); h[3] = bfr(a.w);
  h[4] = bfr(b.x); h[5] = bfr(b.y); h[6] = bfr(b.z); h[7] = bfr(b.w);
  *(u16x8*)dst = h;
}

// ---------------------------------------------------------------------------
// prep: Wall[384][1152] = [ Wq*temp | Wk | Wv@T ]
// ---------------------------------------------------------------------------
__global__ __launch_bounds__(256) void prep_wall(
    const float* __restrict__ Wq, const float* __restrict__ Wk,
    const float* __restrict__ Wv, const float* __restrict__ T,
    const float* __restrict__ temp, float* __restrict__ Wall) {
  int idx = blockIdx.x * 256 + threadIdx.x;   // < 442368
  int d = idx / 1152, c = idx - (idx / 1152) * 1152;
  float v;
  if (c < 384) {
    v = Wq[d * 384 + c] * temp[c / 48];
  } else if (c < 768) {
    v = Wk[d * 384 + (c - 384)];
  } else {
    int n = c - 768;
    int h = n / 48, nn = n - h * 48;
    float s = 0.f;
    for (int m = 0; m < 48; ++m) s += Wv[d * 384 + h * 48 + m] * T[m * 48 + nn];
    v = s;
  }
  Wall[idx] = v;
}

// ---------------------------------------------------------------------------
// generic fp32 GEMM, 64x64 tile, 256 threads, 4x4 microtile. M,N %64==0, K %16==0
// ---------------------------------------------------------------------------
__global__ __launch_bounds__(256) void gemm64(
    const float* __restrict__ A, const float* __restrict__ B,
    float* __restrict__ Cout, int M, int N, int K) {
  __shared__ float As[64][17];
  __shared__ float Bs[16][65];
  int t = threadIdx.x;
  int tx = t & 15, ty = t >> 4;
  int m0 = blockIdx.y * 64, n0 = blockIdx.x * 64;
  float acc[4][4] = {};
  for (int k0 = 0; k0 < K; k0 += 16) {
    __syncthreads();
#pragma unroll
    for (int p = 0; p < 4; ++p) {
      int idx = t + 256 * p;
      int r = idx >> 4, c = idx & 15;
      As[r][c] = A[(size_t)(m0 + r) * K + k0 + c];
    }
#pragma unroll
    for (int p = 0; p < 4; ++p) {
      int idx = t + 256 * p;
      int r = idx >> 6, c = idx & 63;
      Bs[r][c] = B[(size_t)(k0 + r) * N + n0 + c];
    }
    __syncthreads();
#pragma unroll
    for (int kk = 0; kk < 16; ++kk) {
      float a[4], b[4];
#pragma unroll
      for (int i = 0; i < 4; ++i) a[i] = As[ty * 4 + i][kk];
#pragma unroll
      for (int j = 0; j < 4; ++j) b[j] = Bs[kk][tx * 4 + j];
#pragma unroll
      for (int i = 0; i < 4; ++i)
#pragma unroll
        for (int j = 0; j < 4; ++j) acc[i][j] += a[i] * b[j];
    }
  }
#pragma unroll
  for (int i = 0; i < 4; ++i)
#pragma unroll
    for (int j = 0; j < 4; ++j)
      Cout[(size_t)(m0 + ty * 4 + i) * N + n0 + tx * 4 + j] = acc[i][j];
}

// ---------------------------------------------------------------------------
// gate[b,s,h] = sigmoid(curvature[b,s,:] . gate_kernel[:,h])
// ---------------------------------------------------------------------------
__global__ __launch_bounds__(256) void gate_k(
    const float* __restrict__ curv, const float* __restrict__ gk,
    float* __restrict__ gate) {
  int g = blockIdx.x * 256 + threadIdx.x;   // < 8192
  int sg = g >> 3, h = g & 7;
  const float* crow = curv + (size_t)sg * 384;
  float dot = 0.f;
  for (int d = 0; d < 384; ++d) dot += crow[d] * gk[d * 8 + h];
  gate[g] = 1.0f / (1.0f + __expf(-dot));
}

// ---------------------------------------------------------------------------
// gram: C[b][i][j] += sum_k X[b,i,k]*X[b,j,k]
// Triangular 128^2 tiles (10 of 16 per batch), split-K=24, fp32 atomics.
// 256 thr = 4 waves (2m x 2n), wave tile 64x64 -> acc 64 VGPR (no spill).
// LDS double-buffered 2 x (A 16KB | B 16KB) = 64KB -> 2 blocks/CU.
// blockIdx -> (xcd-grouped) so the 10 tiles of one (b,split) share an XCD L2.
// ---------------------------------------------------------------------------
__global__ __launch_bounds__(256, 2) void gram_k(const float* __restrict__ X,
                                                 float* __restrict__ C) {
  static const int TIlut[10] = {0,0,0,0,1,1,1,2,2,3};
  static const int TJlut[10] = {0,1,2,3,1,2,3,2,3,3};
  int bid = blockIdx.x;              // 0..479
  int xcd = bid & 7, slot = bid >> 3;  // slot 0..59
  int g = xcd * 6 + slot / 10;       // group 0..47, 10 tiles contiguous per XCD
  int t10 = slot % 10;
  int b = g & 1;
  int split = g >> 1;                // 0..23
  int ti = TIlut[t10], tj = TJlut[t10];
  bool diag = (ti == tj);
  const float* Xb = X + (size_t)b * S * F;
  int i0 = ti * 128, j0 = tj * 128;
  int k0b = split * GSPAN;

  __shared__ short lds[32768];       // 64KB: [2 buf][A 16KB | B 16KB]
  char* ldsc = (char*)lds;

  int t = threadIdx.x;
  int lane = t & 63, wave = t >> 6;
  int wm = wave >> 1, wn = wave & 1;

  f32x4 acc[4][4];
#pragma unroll
  for (int mt = 0; mt < 4; ++mt)
#pragma unroll
    for (int nt = 0; nt < 4; ++nt) acc[mt][nt] = (f32x4){0.f, 0.f, 0.f, 0.f};

  float4 gA[8], gB[8];

#define ISSUE(dst, rbase, k0v)                                            \
  {                                                                       \
    _Pragma("unroll") for (int q = 0; q < 4; ++q) {                       \
      int pid = q * 256 + t;                                              \
      int row = pid >> 3, kg = pid & 7;                                   \
      const float* src = Xb + (size_t)((rbase) + row) * F + (k0v) + kg * 8; \
      dst[2 * q] = ((const float4*)src)[0];                               \
      dst[2 * q + 1] = ((const float4*)src)[1];                           \
    }                                                                     \
  }

#define WRITEP(base, srcv)                                                \
  {                                                                       \
    _Pragma("unroll") for (int q = 0; q < 4; ++q) {                       \
      int pid = q * 256 + t;                                              \
      int row = pid >> 3, kg = pid & 7;                                   \
      stash((base) + row * 128 + ((kg * 16) ^ ((row & 7) << 4)),          \
            srcv[2 * q], srcv[2 * q + 1]);                                \
    }                                                                     \
  }

  // prologue: stage chunk 0 into buf 0
  ISSUE(gA, i0, k0b);
  if (!diag) ISSUE(gB, j0, k0b);
  WRITEP(ldsc, gA);
  if (!diag) WRITEP(ldsc + 16384, gB);
  __syncthreads();

  for (int ks = 0; ks < GITER; ++ks) {
    int cur = ks & 1;
    const char* pA = ldsc + cur * 32768;
    const char* pB = diag ? pA : (pA + 16384);
    char* wbuf = ldsc + (cur ^ 1) * 32768;
    bool pf = (ks + 1 < GITER);
    int k0n = k0b + (ks + 1) * 64;

    if (pf) {
      ISSUE(gA, i0, k0n);
      if (!diag) ISSUE(gB, j0, k0n);
    }

#pragma unroll
    for (int ksub = 0; ksub < 2; ++ksub) {
      short8 af[4], bfv[4];
      int kb = ksub * 64 + (lane >> 4) * 16;
#pragma unroll
      for (int mt = 0; mt < 4; ++mt) {
        int row = wm * 64 + mt * 16 + (lane & 15);
        af[mt] = *(const short8*)(pA + row * 128 + (kb ^ ((row & 7) << 4)));
      }
#pragma unroll
      for (int nt = 0; nt < 4; ++nt) {
        int row = wn * 64 + nt * 16 + (lane & 15);
        bfv[nt] = *(const short8*)(pB + row * 128 + (kb ^ ((row & 7) << 4)));
      }
#pragma unroll
      for (int mt = 0; mt < 4; ++mt)
#pragma unroll
        for (int nt = 0; nt < 4; ++nt)
          acc[mt][nt] = __builtin_amdgcn_mfma_f32_16x16x32_bf16(
              af[mt], bfv[nt], acc[mt][nt], 0, 0, 0);
    }

    if (pf) {
      WRITEP(wbuf, gA);
      if (!diag) WRITEP(wbuf + 16384, gB);
    }
    __syncthreads();
  }

  // epilogue: C/D layout col=lane&15, row=(lane>>4)*4+reg (C symmetric => robust)
  int cn = lane & 15, r0 = (lane >> 4) * 4;
#pragma unroll
  for (int mt = 0; mt < 4; ++mt)
#pragma unroll
    for (int nt = 0; nt < 4; ++nt)
#pragma unroll
      for (int r = 0; r < 4; ++r) {
        int i = i0 + wm * 64 + mt * 16 + r0 + r;
        int j = j0 + wn * 64 + nt * 16 + cn;
        atomicAdd(&C[((size_t)b * S + i) * S + j], acc[mt][nt][r]);
      }
#undef ISSUE
#undef WRITEP
}

// ---------------------------------------------------------------------------
// mirror: C[b][i][j] = C[b][j][i] for all strict-lower 64x64 pairs (I>J).
// Overlap with diagonal-128-tile interiors rewrites identical values.
// ---------------------------------------------------------------------------
__global__ __launch_bounds__(256) void mirror_k(float* __restrict__ C) {
  static const int MI[28] = {1,2,2,3,3,3,4,4,4,4,5,5,5,5,5,6,6,6,6,6,6,7,7,7,7,7,7,7};
  static const int MJ[28] = {0,0,1,0,1,2,0,1,2,3,0,1,2,3,4,0,1,2,3,4,5,0,1,2,3,4,5,6};
  int bid = blockIdx.x;
  int b = bid / 28, p = bid - (bid / 28) * 28;
  int I = MI[p], J = MJ[p];
  __shared__ float tile[64][65];
  int t = threadIdx.x;
  int tx = t & 63, ty = t >> 6;
#pragma unroll
  for (int r = 0; r < 64; r += 4)
    tile[r + ty][tx] = C[((size_t)b * 512 + J * 64 + r + ty) * 512 + I * 64 + tx];
  __syncthreads();
#pragma unroll
  for (int r = 0; r < 64; r += 4)
    C[((size_t)b * 512 + I * 64 + r + ty) * 512 + J * 64 + tx] = tile[tx][r + ty];
}

// ---------------------------------------------------------------------------
// scores + softmax, wave-per-row:
// attn[b,h,i,j] = softmax_j( (q'_i.k_j + 0.1*temp_h*hol_ij) * gate[b,j,h] )
// ---------------------------------------------------------------------------
__global__ __launch_bounds__(256) void scores_softmax(
    const float* __restrict__ qkv, const float* __restrict__ gate,
    const float* __restrict__ C, const float* __restrict__ temp,
    float* __restrict__ attn) {
  int bid = blockIdx.x;
  int b = bid >> 6;
  int rem = bid & 63;
  int h = rem >> 3;
  int ic = rem & 7;
  int i0 = ic * 64;

  __shared__ float kh[512][49];
  __shared__ float qs[64][48];
  __shared__ float gs[512];
  __shared__ float sqv[512];

  int t = threadIdx.x;
  const float invF = 1.0f / 147456.0f;
  float ch = 0.1f * temp[h];

  for (int idx = t; idx < 512 * 48; idx += 256) {
    int s = idx / 48, kd = idx - (idx / 48) * 48;
    kh[s][kd] = qkv[(size_t)(b * S + s) * 1152 + 384 + h * 48 + kd];
  }
  for (int idx = t; idx < 64 * 48; idx += 256) {
    int r = idx / 48, kd = idx - (idx / 48) * 48;
    qs[r][kd] = qkv[(size_t)(b * S + i0 + r) * 1152 + h * 48 + kd];
  }
  for (int j = t; j < 512; j += 256) {
    gs[j] = gate[(b * S + j) * 8 + h];
    sqv[j] = C[((size_t)b * S + j) * S + j] * invF;
  }
  __syncthreads();

  int lane = t & 63, wv = t >> 6;
  for (int rr = 0; rr < 16; ++rr) {
    int r = wv * 16 + rr;
    int i = i0 + r;
    const float* Crow = C + ((size_t)b * S + i) * S;
    float sqi = sqv[i];
    float sc[8];
#pragma unroll
    for (int jj = 0; jj < 8; ++jj) {
      int j = jj * 64 + lane;
      float dot = 0.f;
#pragma unroll
      for (int kd = 0; kd < 48; ++kd) dot += qs[r][kd] * kh[j][kd];
      sc[jj] = (dot + ch * (2.0f * Crow[j] * invF - sqi - sqv[j])) * gs[j];
    }
    float m = sc[0];
#pragma unroll
    for (int jj = 1; jj < 8; ++jj) m = fmaxf(m, sc[jj]);
#pragma unroll
    for (int off = 32; off; off >>= 1) m = fmaxf(m, __shfl_xor(m, off));
    float e[8];
    float sum = 0.f;
#pragma unroll
    for (int jj = 0; jj < 8; ++jj) { e[jj] = __expf(sc[jj] - m); sum += e[jj]; }
#pragma unroll
    for (int off = 32; off; off >>= 1) sum += __shfl_xor(sum, off);
    float inv = 1.0f / sum;
    float* arow = attn + (((size_t)(b * 8 + h)) * S + i) * S;
#pragma unroll
    for (int jj = 0; jj < 8; ++jj) arow[jj * 64 + lane] = e[jj] * inv;
  }
}

// ---------------------------------------------------------------------------
// PV: ctx[b,i,h,m] = sum_j attn[b,h,i,j] * v_t[b,j,h,m]. block=(b,h,64 rows)
// ---------------------------------------------------------------------------
__global__ __launch_bounds__(256) void pv_k(const float* __restrict__ attn,
                                            const float* __restrict__ qkv,
                                            float* __restrict__ ctx) {
  int bid = blockIdx.x;
  int b = bid >> 6;
  int rem = bid & 63;
  int h = rem >> 3;
  int ic = rem & 7;
  int i0 = ic * 64;

  __shared__ float vts[64][48];
  __shared__ float ats[64][65];
  int t = threadIdx.x;
  int tx = t & 15, ty = t >> 4;
  int r0 = ty * 4, m0 = tx * 3;
  float acc[4][3] = {};
  for (int jc = 0; jc < 8; ++jc) {
    __syncthreads();
    for (int idx = t; idx < 3072; idx += 256) {
      int jr = idx / 48, m = idx - (idx / 48) * 48;
      vts[jr][m] = qkv[(size_t)(b * S + jc * 64 + jr) * 1152 + 768 + h * 48 + m];
    }
    for (int idx = t; idx < 4096; idx += 256) {
      int r = idx >> 6, j = idx & 63;
      ats[r][j] = attn[(((size_t)(b * 8 + h)) * S + i0 + r) * S + jc * 64 + j];
    }
    __syncthreads();
#pragma unroll 4
    for (int jj = 0; jj < 64; ++jj) {
      float bv0 = vts[jj][m0], bv1 = vts[jj][m0 + 1], bv2 = vts[jj][m0 + 2];
#pragma unroll
      for (int ii = 0; ii < 4; ++ii) {
        float av = ats[r0 + ii][jj];
        acc[ii][0] += av * bv0;
        acc[ii][1] += av * bv1;
        acc[ii][2] += av * bv2;
      }
    }
  }
#pragma unroll
  for (int ii = 0; ii < 4; ++ii)
#pragma unroll
    for (int jm = 0; jm < 3; ++jm)
      ctx[(size_t)(b * S + i0 + r0 + ii) * 384 + h * 48 + m0 + jm] = acc[ii][jm];
}

// ---------------------------------------------------------------------------
extern "C" void kernel_launch(void* const* d_in, const int* in_sizes, int n_in,
                              void* d_out, int out_size, void* d_ws, size_t ws_size,
                              hipStream_t stream) {
  const float* emb  = (const float*)d_in[0];
  const float* curv = (const float*)d_in[1];
  const float* conn = (const float*)d_in[2];
  const float* Wq   = (const float*)d_in[3];
  const float* Wk   = (const float*)d_in[4];
  const float* Wv   = (const float*)d_in[5];
  const float* Wo   = (const float*)d_in[6];
  const float* gk   = (const float*)d_in[7];
  const float* T    = (const float*)d_in[8];
  const float* temp = (const float*)d_in[9];

  float* ws   = (float*)d_ws;
  float* C    = ws;                    // 524288          (2MB)
  float* qkv  = ws + 524288;           // 1179648: [1024][ q' | k | v_t ]
  float* gate = ws + 1703936;          // 8192
  float* Wall = ws + 1712128;          // 442368
  float* attn = ws + 2154496;          // 4194304         (16MB)
  float* ctx  = ws + 6348800;          // 393216   -> total ~27MB

  hipMemsetAsync(C, 0, 524288 * sizeof(float), stream);
  prep_wall<<<1728, 256, 0, stream>>>(Wq, Wk, Wv, T, temp, Wall);
  gemm64<<<dim3(18, 16), 256, 0, stream>>>(emb, Wall, qkv, 1024, 1152, 384);
  gate_k<<<32, 256, 0, stream>>>(curv, gk, gate);
  gram_k<<<480, 256, 0, stream>>>(conn, C);
  mirror_k<<<56, 256, 0, stream>>>(C);
  scores_softmax<<<128, 256, 0, stream>>>(qkv, gate, C, temp, attn);
  pv_k<<<128, 256, 0, stream>>>(attn, qkv, ctx);
  gemm64<<<dim3(6, 16), 256, 0, stream>>>(ctx, Wo, (float*)d_out, 1024, 384, 384);
}

// Round 4
// 440.351 us; speedup vs baseline: 1.3146x; 1.0771x over previous
//
#include <hip/hip_runtime.h>
#include <hip/hip_bf16.h>

#define S 512
#define D 384
#define H 8
#define F 147456             // D*D
#define GSPLIT 24
#define GSPAN (F / GSPLIT)   // 6144
#define GITER (GSPAN / 64)   // 96

typedef __attribute__((ext_vector_type(8))) short short8;
typedef __attribute__((ext_vector_type(8))) unsigned short u16x8;
typedef __attribute__((ext_vector_type(4))) float f32x4;

__device__ inline unsigned short bfr(float x) {
  return __builtin_bit_cast(unsigned short, __float2bfloat16(x));
}

__device__ inline void stash(void* dst, float4 a, float4 b) {
  u16x8 h;
  h[0] = bfr(a.x); h[1] = bfr(a.y); h[2] = bfr(a.z); h[3] = bfr(a.w);
  h[4] = bfr(b.x); h[5] = bfr(b.y); h[6] = bfr(b.z); h[7] = bfr(b.w);
  *(u16x8*)dst = h;
}

// ---------------------------------------------------------------------------
// prep: Wall[384][1152] = [ Wq*temp | Wk | Wv@T ]
// ---------------------------------------------------------------------------
__global__ __launch_bounds__(256) void prep_wall(
    const float* __restrict__ Wq, const float* __restrict__ Wk,
    const float* __restrict__ Wv, const float* __restrict__ T,
    const float* __restrict__ temp, float* __restrict__ Wall) {
  int idx = blockIdx.x * 256 + threadIdx.x;   // < 442368
  int d = idx / 1152, c = idx - (idx / 1152) * 1152;
  float v;
  if (c < 384) {
    v = Wq[d * 384 + c] * temp[c / 48];
  } else if (c < 768) {
    v = Wk[d * 384 + (c - 384)];
  } else {
    int n = c - 768;
    int h = n / 48, nn = n - h * 48;
    float s = 0.f;
    for (int m = 0; m < 48; ++m) s += Wv[d * 384 + h * 48 + m] * T[m * 48 + nn];
    v = s;
  }
  Wall[idx] = v;
}

// ---------------------------------------------------------------------------
// generic fp32 GEMM, 64x64 tile, 256 threads, 4x4 microtile. M,N %64==0, K %16==0
// ---------------------------------------------------------------------------
__global__ __launch_bounds__(256) void gemm64(
    const float* __restrict__ A, const float* __restrict__ B,
    float* __restrict__ Cout, int M, int N, int K) {
  __shared__ float As[64][17];
  __shared__ float Bs[16][65];
  int t = threadIdx.x;
  int tx = t & 15, ty = t >> 4;
  int m0 = blockIdx.y * 64, n0 = blockIdx.x * 64;
  float acc[4][4] = {};
  for (int k0 = 0; k0 < K; k0 += 16) {
    __syncthreads();
#pragma unroll
    for (int p = 0; p < 4; ++p) {
      int idx = t + 256 * p;
      int r = idx >> 4, c = idx & 15;
      As[r][c] = A[(size_t)(m0 + r) * K + k0 + c];
    }
#pragma unroll
    for (int p = 0; p < 4; ++p) {
      int idx = t + 256 * p;
      int r = idx >> 6, c = idx & 63;
      Bs[r][c] = B[(size_t)(k0 + r) * N + n0 + c];
    }
    __syncthreads();
#pragma unroll
    for (int kk = 0; kk < 16; ++kk) {
      float a[4], b[4];
#pragma unroll
      for (int i = 0; i < 4; ++i) a[i] = As[ty * 4 + i][kk];
#pragma unroll
      for (int j = 0; j < 4; ++j) b[j] = Bs[kk][tx * 4 + j];
#pragma unroll
      for (int i = 0; i < 4; ++i)
#pragma unroll
        for (int j = 0; j < 4; ++j) acc[i][j] += a[i] * b[j];
    }
  }
#pragma unroll
  for (int i = 0; i < 4; ++i)
#pragma unroll
    for (int j = 0; j < 4; ++j)
      Cout[(size_t)(m0 + ty * 4 + i) * N + n0 + tx * 4 + j] = acc[i][j];
}

// ---------------------------------------------------------------------------
// gate[b,s,h] = sigmoid(curvature[b,s,:] . gate_kernel[:,h])
// ---------------------------------------------------------------------------
__global__ __launch_bounds__(256) void gate_k(
    const float* __restrict__ curv, const float* __restrict__ gk,
    float* __restrict__ gate) {
  int g = blockIdx.x * 256 + threadIdx.x;   // < 8192
  int sg = g >> 3, h = g & 7;
  const float* crow = curv + (size_t)sg * 384;
  float dot = 0.f;
  for (int d = 0; d < 384; ++d) dot += crow[d] * gk[d * 8 + h];
  gate[g] = 1.0f / (1.0f + __expf(-dot));
}

// ---------------------------------------------------------------------------
// gram: part[(b*10+t10)][split][128*128] = sum_{k in split} X_i . X_j
// Triangular 128^2 tiles (10 of 16 per batch), split-K=24, PLAIN STORES
// (no atomics). 256 thr = 4 waves (2m x 2n), wave tile 64x64.
// LDS double-buffered 2 x (A 16KB | B 16KB) = 64KB -> 2 blocks/CU.
// ---------------------------------------------------------------------------
__global__ __launch_bounds__(256, 2) void gram_k(const float* __restrict__ X,
                                                 float* __restrict__ part) {
  static const int TIlut[10] = {0,0,0,0,1,1,1,2,2,3};
  static const int TJlut[10] = {0,1,2,3,1,2,3,2,3,3};
  int bid = blockIdx.x;              // 0..479
  int xcd = bid & 7, slot = bid >> 3;  // slot 0..59
  int g = xcd * 6 + slot / 10;       // group 0..47, 10 tiles contiguous per XCD
  int t10 = slot % 10;
  int b = g & 1;
  int split = g >> 1;                // 0..23
  int ti = TIlut[t10], tj = TJlut[t10];
  bool diag = (ti == tj);
  const float* Xb = X + (size_t)b * S * F;
  int i0 = ti * 128, j0 = tj * 128;
  int k0b = split * GSPAN;

  __shared__ short lds[32768];       // 64KB: [2 buf][A 16KB | B 16KB]
  char* ldsc = (char*)lds;

  int t = threadIdx.x;
  int lane = t & 63, wave = t >> 6;
  int wm = wave >> 1, wn = wave & 1;

  f32x4 acc[4][4];
#pragma unroll
  for (int mt = 0; mt < 4; ++mt)
#pragma unroll
    for (int nt = 0; nt < 4; ++nt) acc[mt][nt] = (f32x4){0.f, 0.f, 0.f, 0.f};

  float4 gA[8], gB[8];

#define ISSUE(dst, rbase, k0v)                                            \
  {                                                                       \
    _Pragma("unroll") for (int q = 0; q < 4; ++q) {                       \
      int pid = q * 256 + t;                                              \
      int row = pid >> 3, kg = pid & 7;                                   \
      const float* src = Xb + (size_t)((rbase) + row) * F + (k0v) + kg * 8; \
      dst[2 * q] = ((const float4*)src)[0];                               \
      dst[2 * q + 1] = ((const float4*)src)[1];                           \
    }                                                                     \
  }

#define WRITEP(base, srcv)                                                \
  {                                                                       \
    _Pragma("unroll") for (int q = 0; q < 4; ++q) {                       \
      int pid = q * 256 + t;                                              \
      int row = pid >> 3, kg = pid & 7;                                   \
      stash((base) + row * 128 + ((kg * 16) ^ ((row & 7) << 4)),          \
            srcv[2 * q], srcv[2 * q + 1]);                                \
    }                                                                     \
  }

  // prologue: stage chunk 0 into buf 0
  ISSUE(gA, i0, k0b);
  if (!diag) ISSUE(gB, j0, k0b);
  WRITEP(ldsc, gA);
  if (!diag) WRITEP(ldsc + 16384, gB);
  __syncthreads();

  for (int ks = 0; ks < GITER; ++ks) {
    int cur = ks & 1;
    const char* pA = ldsc + cur * 32768;
    const char* pB = diag ? pA : (pA + 16384);
    char* wbuf = ldsc + (cur ^ 1) * 32768;
    bool pf = (ks + 1 < GITER);
    int k0n = k0b + (ks + 1) * 64;

    if (pf) {
      ISSUE(gA, i0, k0n);
      if (!diag) ISSUE(gB, j0, k0n);
    }

#pragma unroll
    for (int ksub = 0; ksub < 2; ++ksub) {
      short8 af[4], bfv[4];
      int kb = ksub * 64 + (lane >> 4) * 16;
#pragma unroll
      for (int mt = 0; mt < 4; ++mt) {
        int row = wm * 64 + mt * 16 + (lane & 15);
        af[mt] = *(const short8*)(pA + row * 128 + (kb ^ ((row & 7) << 4)));
      }
#pragma unroll
      for (int nt = 0; nt < 4; ++nt) {
        int row = wn * 64 + nt * 16 + (lane & 15);
        bfv[nt] = *(const short8*)(pB + row * 128 + (kb ^ ((row & 7) << 4)));
      }
#pragma unroll
      for (int mt = 0; mt < 4; ++mt)
#pragma unroll
        for (int nt = 0; nt < 4; ++nt)
          acc[mt][nt] = __builtin_amdgcn_mfma_f32_16x16x32_bf16(
              af[mt], bfv[nt], acc[mt][nt], 0, 0, 0);
    }

    if (pf) {
      WRITEP(wbuf, gA);
      if (!diag) WRITEP(wbuf + 16384, gB);
    }
    __syncthreads();
  }

  // epilogue: plain stores to packed partial tile.
  // C/D layout col=lane&15, row=(lane>>4)*4+reg (C symmetric => robust)
  float* dst = part + ((size_t)(b * 10 + t10) * 24 + split) * 16384;
  int cn = lane & 15, r0 = (lane >> 4) * 4;
#pragma unroll
  for (int mt = 0; mt < 4; ++mt)
#pragma unroll
    for (int nt = 0; nt < 4; ++nt)
#pragma unroll
      for (int r = 0; r < 4; ++r) {
        int i = wm * 64 + mt * 16 + r0 + r;
        int j = wn * 64 + nt * 16 + cn;
        dst[i * 128 + j] = acc[mt][nt][r];
      }
#undef ISSUE
#undef WRITEP
}

// ---------------------------------------------------------------------------
// reduce: C upper tiles = sum over 24 splits of part.  320 blocks x 256 thr.
// ---------------------------------------------------------------------------
__global__ __launch_bounds__(256) void reduce_k(const float* __restrict__ part,
                                                float* __restrict__ C) {
  static const int TIlut[10] = {0,0,0,0,1,1,1,2,2,3};
  static const int TJlut[10] = {0,1,2,3,1,2,3,2,3,3};
  int blk = blockIdx.x;             // 0..319
  int tile = blk >> 4;              // 0..19
  int seg = blk & 15;
  int b = tile / 10, t10 = tile - (tile / 10) * 10;
  int ti = TIlut[t10], tj = TJlut[t10];
  const float* p0 = part + (size_t)tile * 24 * 16384;
  int e = seg * 1024 + threadIdx.x * 4;
  float4 s = {0.f, 0.f, 0.f, 0.f};
#pragma unroll
  for (int sp = 0; sp < 24; ++sp) {
    float4 v = *(const float4*)(p0 + (size_t)sp * 16384 + e);
    s.x += v.x; s.y += v.y; s.z += v.z; s.w += v.w;
  }
  int r = e >> 7, c = e & 127;
  *(float4*)(&C[((size_t)b * 512 + ti * 128 + r) * 512 + tj * 128 + c]) = s;
}

// ---------------------------------------------------------------------------
// mirror: C[b][i][j] = C[b][j][i] for all strict-lower 64x64 pairs (I>J).
// ---------------------------------------------------------------------------
__global__ __launch_bounds__(256) void mirror_k(float* __restrict__ C) {
  static const int MI[28] = {1,2,2,3,3,3,4,4,4,4,5,5,5,5,5,6,6,6,6,6,6,7,7,7,7,7,7,7};
  static const int MJ[28] = {0,0,1,0,1,2,0,1,2,3,0,1,2,3,4,0,1,2,3,4,5,0,1,2,3,4,5,6};
  int bid = blockIdx.x;
  int b = bid / 28, p = bid - (bid / 28) * 28;
  int I = MI[p], J = MJ[p];
  __shared__ float tile[64][65];
  int t = threadIdx.x;
  int tx = t & 63, ty = t >> 6;
#pragma unroll
  for (int r = 0; r < 64; r += 4)
    tile[r + ty][tx] = C[((size_t)b * 512 + J * 64 + r + ty) * 512 + I * 64 + tx];
  __syncthreads();
#pragma unroll
  for (int r = 0; r < 64; r += 4)
    C[((size_t)b * 512 + I * 64 + r + ty) * 512 + J * 64 + tx] = tile[tx][r + ty];
}

// ---------------------------------------------------------------------------
// scores + softmax, wave-per-row, 32-row chunks (256 blocks = full GPU):
// attn[b,h,i,j] = softmax_j( (q'_i.k_j + 0.1*temp_h*hol_ij) * gate[b,j,h] )
// ---------------------------------------------------------------------------
__global__ __launch_bounds__(256) void scores_softmax(
    const float* __restrict__ qkv, const float* __restrict__ gate,
    const float* __restrict__ C, const float* __restrict__ temp,
    float* __restrict__ attn) {
  int bid = blockIdx.x;
  int b = bid >> 7;
  int rem = bid & 127;
  int h = rem >> 4;
  int ic = rem & 15;
  int i0 = ic * 32;

  __shared__ float kh[512][49];
  __shared__ float qs[32][48];
  __shared__ float gs[512];
  __shared__ float sqv[512];

  int t = threadIdx.x;
  const float invF = 1.0f / 147456.0f;
  float ch = 0.1f * temp[h];

  for (int idx = t; idx < 512 * 48; idx += 256) {
    int s = idx / 48, kd = idx - (idx / 48) * 48;
    kh[s][kd] = qkv[(size_t)(b * S + s) * 1152 + 384 + h * 48 + kd];
  }
  for (int idx = t; idx < 32 * 48; idx += 256) {
    int r = idx / 48, kd = idx - (idx / 48) * 48;
    qs[r][kd] = qkv[(size_t)(b * S + i0 + r) * 1152 + h * 48 + kd];
  }
  for (int j = t; j < 512; j += 256) {
    gs[j] = gate[(b * S + j) * 8 + h];
    sqv[j] = C[((size_t)b * S + j) * S + j] * invF;
  }
  __syncthreads();

  int lane = t & 63, wv = t >> 6;
  for (int rr = 0; rr < 8; ++rr) {
    int r = wv * 8 + rr;
    int i = i0 + r;
    const float* Crow = C + ((size_t)b * S + i) * S;
    float sqi = sqv[i];
    float sc[8];
#pragma unroll
    for (int jj = 0; jj < 8; ++jj) {
      int j = jj * 64 + lane;
      float dot = 0.f;
#pragma unroll
      for (int kd = 0; kd < 48; ++kd) dot += qs[r][kd] * kh[j][kd];
      sc[jj] = (dot + ch * (2.0f * Crow[j] * invF - sqi - sqv[j])) * gs[j];
    }
    float m = sc[0];
#pragma unroll
    for (int jj = 1; jj < 8; ++jj) m = fmaxf(m, sc[jj]);
#pragma unroll
    for (int off = 32; off; off >>= 1) m = fmaxf(m, __shfl_xor(m, off));
    float e[8];
    float sum = 0.f;
#pragma unroll
    for (int jj = 0; jj < 8; ++jj) { e[jj] = __expf(sc[jj] - m); sum += e[jj]; }
#pragma unroll
    for (int off = 32; off; off >>= 1) sum += __shfl_xor(sum, off);
    float inv = 1.0f / sum;
    float* arow = attn + (((size_t)(b * 8 + h)) * S + i) * S;
#pragma unroll
    for (int jj = 0; jj < 8; ++jj) arow[jj * 64 + lane] = e[jj] * inv;
  }
}

// ---------------------------------------------------------------------------
// PV: ctx[b,i,h,m] = sum_j attn[b,h,i,j] * v_t[b,j,h,m]. block=(b,h,32 rows)
// ---------------------------------------------------------------------------
__global__ __launch_bounds__(256) void pv_k(const float* __restrict__ attn,
                                            const float* __restrict__ qkv,
                                            float* __restrict__ ctx) {
  int bid = blockIdx.x;
  int b = bid >> 7;
  int rem = bid & 127;
  int h = rem >> 4;
  int ic = rem & 15;
  int i0 = ic * 32;

  __shared__ float vts[64][48];
  __shared__ float ats[32][65];
  int t = threadIdx.x;
  int tx = t & 15, ty = t >> 4;
  int r0 = ty * 2, m0 = tx * 3;
  float acc[2][3] = {};
  for (int jc = 0; jc < 8; ++jc) {
    __syncthreads();
    for (int idx = t; idx < 3072; idx += 256) {
      int jr = idx / 48, m = idx - (idx / 48) * 48;
      vts[jr][m] = qkv[(size_t)(b * S + jc * 64 + jr) * 1152 + 768 + h * 48 + m];
    }
    for (int idx = t; idx < 2048; idx += 256) {
      int r = idx >> 6, j = idx & 63;
      ats[r][j] = attn[(((size_t)(b * 8 + h)) * S + i0 + r) * S + jc * 64 + j];
    }
    __syncthreads();
#pragma unroll 4
    for (int jj = 0; jj < 64; ++jj) {
      float bv0 = vts[jj][m0], bv1 = vts[jj][m0 + 1], bv2 = vts[jj][m0 + 2];
#pragma unroll
      for (int ii = 0; ii < 2; ++ii) {
        float av = ats[r0 + ii][jj];
        acc[ii][0] += av * bv0;
        acc[ii][1] += av * bv1;
        acc[ii][2] += av * bv2;
      }
    }
  }
#pragma unroll
  for (int ii = 0; ii < 2; ++ii)
#pragma unroll
    for (int jm = 0; jm < 3; ++jm)
      ctx[(size_t)(b * S + i0 + r0 + ii) * 384 + h * 48 + m0 + jm] = acc[ii][jm];
}

// ---------------------------------------------------------------------------
extern "C" void kernel_launch(void* const* d_in, const int* in_sizes, int n_in,
                              void* d_out, int out_size, void* d_ws, size_t ws_size,
                              hipStream_t stream) {
  const float* emb  = (const float*)d_in[0];
  const float* curv = (const float*)d_in[1];
  const float* conn = (const float*)d_in[2];
  const float* Wq   = (const float*)d_in[3];
  const float* Wk   = (const float*)d_in[4];
  const float* Wv   = (const float*)d_in[5];
  const float* Wo   = (const float*)d_in[6];
  const float* gk   = (const float*)d_in[7];
  const float* T    = (const float*)d_in[8];
  const float* temp = (const float*)d_in[9];

  float* ws   = (float*)d_ws;
  float* C    = ws;                    // 524288          (2MB)
  float* qkv  = ws + 524288;           // 1179648: [1024][ q' | k | v_t ]
  float* gate = ws + 1703936;          // 8192
  float* Wall = ws + 1712128;          // 442368
  float* attn = ws + 2154496;          // 4194304         (16MB)
  float* ctx  = ws + 6348800;          // 393216
  float* part = ws + 6742016;          // 7864320         (30MB) -> ~58MB total

  prep_wall<<<1728, 256, 0, stream>>>(Wq, Wk, Wv, T, temp, Wall);
  gemm64<<<dim3(18, 16), 256, 0, stream>>>(emb, Wall, qkv, 1024, 1152, 384);
  gate_k<<<32, 256, 0, stream>>>(curv, gk, gate);
  gram_k<<<480, 256, 0, stream>>>(conn, part);
  reduce_k<<<320, 256, 0, stream>>>(part, C);
  mirror_k<<<56, 256, 0, stream>>>(C);
  scores_softmax<<<256, 256, 0, stream>>>(qkv, gate, C, temp, attn);
  pv_k<<<256, 256, 0, stream>>>(attn, qkv, ctx);
  gemm64<<<dim3(6, 16), 256, 0, stream>>>(ctx, Wo, (float*)d_out, 1024, 384, 384);
}

// Round 5
// 394.039 us; speedup vs baseline: 1.4692x; 1.1175x over previous
//
#include <hip/hip_runtime.h>
#include <hip/hip_bf16.h>

#define S 512
#define D 384
#define H 8
#define F 147456             // D*D
#define NSPLIT 40
#define KCHUNKS 2304         // F/64

typedef __attribute__((ext_vector_type(8))) short short8;
typedef __attribute__((ext_vector_type(8))) unsigned short u16x8;
typedef __attribute__((ext_vector_type(4))) float f32x4;

__device__ inline unsigned short bfr(float x) {
  return __builtin_bit_cast(unsigned short, __float2bfloat16(x));
}

__device__ inline void stash(void* dst, float4 a, float4 b) {
  u16x8 h;
  h[0] = bfr(a.x); h[1] = bfr(a.y); h[2] = bfr(a.z); h[3] = bfr(a.w);
  h[4] = bfr(b.x); h[5] = bfr(b.y); h[6] = bfr(b.z); h[7] = bfr(b.w);
  *(u16x8*)dst = h;
}

// ---------------------------------------------------------------------------
// prep: Wall[384][1152] = [ Wq*temp | Wk | Wv@T ]
// ---------------------------------------------------------------------------
__global__ __launch_bounds__(256) void prep_wall(
    const float* __restrict__ Wq, const float* __restrict__ Wk,
    const float* __restrict__ Wv, const float* __restrict__ T,
    const float* __restrict__ temp, float* __restrict__ Wall) {
  int idx = blockIdx.x * 256 + threadIdx.x;   // < 442368
  int d = idx / 1152, c = idx - (idx / 1152) * 1152;
  float v;
  if (c < 384) {
    v = Wq[d * 384 + c] * temp[c / 48];
  } else if (c < 768) {
    v = Wk[d * 384 + (c - 384)];
  } else {
    int n = c - 768;
    int h = n / 48, nn = n - h * 48;
    float s = 0.f;
    for (int m = 0; m < 48; ++m) s += Wv[d * 384 + h * 48 + m] * T[m * 48 + nn];
    v = s;
  }
  Wall[idx] = v;
}

// ---------------------------------------------------------------------------
// generic fp32 GEMM, 64x64 tile, 256 threads, 4x4 microtile. M,N %64==0, K %16==0
// ---------------------------------------------------------------------------
__global__ __launch_bounds__(256) void gemm64(
    const float* __restrict__ A, const float* __restrict__ B,
    float* __restrict__ Cout, int M, int N, int K) {
  __shared__ float As[64][17];
  __shared__ float Bs[16][65];
  int t = threadIdx.x;
  int tx = t & 15, ty = t >> 4;
  int m0 = blockIdx.y * 64, n0 = blockIdx.x * 64;
  float acc[4][4] = {};
  for (int k0 = 0; k0 < K; k0 += 16) {
    __syncthreads();
#pragma unroll
    for (int p = 0; p < 4; ++p) {
      int idx = t + 256 * p;
      int r = idx >> 4, c = idx & 15;
      As[r][c] = A[(size_t)(m0 + r) * K + k0 + c];
    }
#pragma unroll
    for (int p = 0; p < 4; ++p) {
      int idx = t + 256 * p;
      int r = idx >> 6, c = idx & 63;
      Bs[r][c] = B[(size_t)(k0 + r) * N + n0 + c];
    }
    __syncthreads();
#pragma unroll
    for (int kk = 0; kk < 16; ++kk) {
      float a[4], b[4];
#pragma unroll
      for (int i = 0; i < 4; ++i) a[i] = As[ty * 4 + i][kk];
#pragma unroll
      for (int j = 0; j < 4; ++j) b[j] = Bs[kk][tx * 4 + j];
#pragma unroll
      for (int i = 0; i < 4; ++i)
#pragma unroll
        for (int j = 0; j < 4; ++j) acc[i][j] += a[i] * b[j];
    }
  }
#pragma unroll
  for (int i = 0; i < 4; ++i)
#pragma unroll
    for (int j = 0; j < 4; ++j)
      Cout[(size_t)(m0 + ty * 4 + i) * N + n0 + tx * 4 + j] = acc[i][j];
}

// ---------------------------------------------------------------------------
// gate[b,s,h] = sigmoid(curvature[b,s,:] . gate_kernel[:,h])
// ---------------------------------------------------------------------------
__global__ __launch_bounds__(256) void gate_k(
    const float* __restrict__ curv, const float* __restrict__ gk,
    float* __restrict__ gate) {
  int g = blockIdx.x * 256 + threadIdx.x;   // < 8192
  int sg = g >> 3, h = g & 7;
  const float* crow = curv + (size_t)sg * 384;
  float dot = 0.f;
  for (int d = 0; d < 384; ++d) dot += crow[d] * gk[d * 8 + h];
  gate[g] = 1.0f / (1.0f + __expf(-dot));
}

// ---------------------------------------------------------------------------
// gram: bf16 partials, 256^2 triangular tiles (3/batch), runtime split-K=40.
// 512 thr = 8 waves (2m x 4n), wave tile 128x64; acc 128 VGPR, <=256 total.
// UNIFORM staging: every block stages A and B panels (diag stages its panel
// twice -> identical per-iter pacing across the 3 tiles of a (b,split) group
// -> lockstep -> co-XCD L2 reuse can hold). LDS dbuf 2x(A32K|B32K)=128KB.
// bid&7 = XCD; 240 = 8 x 30; 3 consecutive slots = one (b,split) group.
// ---------------------------------------------------------------------------
__global__ __launch_bounds__(512, 2) void gram_k(const float* __restrict__ X,
                                                 unsigned short* __restrict__ part) {
  int bid = blockIdx.x;                // 0..239
  int xcd = bid & 7, slot = bid >> 3;  // slot 0..29
  int grp = xcd * 10 + slot / 3;       // 0..79
  int tile = slot % 3;                 // 0:(0,0) 1:(0,1) 2:(1,1)
  int b = grp & 1;
  int split = grp >> 1;                // 0..39
  int ti = (tile == 2) ? 1 : 0;
  int tj = (tile == 0) ? 0 : 1;
  const float* Xb = X + (size_t)b * S * F;
  int i0 = ti * 256, j0 = tj * 256;
  int kcb = (KCHUNKS * split) / NSPLIT;
  int kce = (KCHUNKS * (split + 1)) / NSPLIT;

  __shared__ short lds[65536];         // 128KB: [2 buf][A 32KB | B 32KB]
  char* ldsc = (char*)lds;

  int t = threadIdx.x;
  int lane = t & 63, wave = t >> 6;
  int wm = wave >> 2, wn = wave & 3;   // 2 x 4 wave grid

  f32x4 acc[8][4];
#pragma unroll
  for (int mt = 0; mt < 8; ++mt)
#pragma unroll
    for (int nt = 0; nt < 4; ++nt) acc[mt][nt] = (f32x4){0.f, 0.f, 0.f, 0.f};

  float4 gA[8], gB[8];

#define ISSUE(dst, rbase, kc)                                               \
  {                                                                         \
    _Pragma("unroll") for (int q = 0; q < 4; ++q) {                         \
      int pid = q * 512 + t;                                                \
      int row = pid >> 3, kg = pid & 7;                                     \
      const float* src =                                                    \
          Xb + (size_t)((rbase) + row) * F + (size_t)(kc) * 64 + kg * 8;    \
      dst[2 * q] = ((const float4*)src)[0];                                 \
      dst[2 * q + 1] = ((const float4*)src)[1];                             \
    }                                                                       \
  }

#define WRITEP(base, srcv)                                                  \
  {                                                                         \
    _Pragma("unroll") for (int q = 0; q < 4; ++q) {                         \
      int pid = q * 512 + t;                                                \
      int row = pid >> 3, kg = pid & 7;                                     \
      stash((base) + row * 128 + ((kg * 16) ^ ((row & 7) << 4)),            \
            srcv[2 * q], srcv[2 * q + 1]);                                  \
    }                                                                       \
  }

#define COMPUTE(ksub)                                                       \
  {                                                                         \
    short8 af[8], bfv[4];                                                   \
    int kb = (ksub) * 64 + (lane >> 4) * 16;                                \
    _Pragma("unroll") for (int mt = 0; mt < 8; ++mt) {                      \
      int row = wm * 128 + mt * 16 + (lane & 15);                           \
      af[mt] = *(const short8*)(pA + row * 128 + (kb ^ ((row & 7) << 4)));  \
    }                                                                       \
    _Pragma("unroll") for (int nt = 0; nt < 4; ++nt) {                      \
      int row = wn * 64 + nt * 16 + (lane & 15);                            \
      bfv[nt] = *(const short8*)(pB + row * 128 + (kb ^ ((row & 7) << 4))); \
    }                                                                       \
    _Pragma("unroll") for (int mt = 0; mt < 8; ++mt)                        \
        _Pragma("unroll") for (int nt = 0; nt < 4; ++nt)                    \
            acc[mt][nt] = __builtin_amdgcn_mfma_f32_16x16x32_bf16(          \
                af[mt], bfv[nt], acc[mt][nt], 0, 0, 0);                     \
  }

  // prologue: stage chunk kcb into buf 0
  ISSUE(gA, i0, kcb);
  WRITEP(ldsc, gA);
  ISSUE(gB, j0, kcb);
  WRITEP(ldsc + 32768, gB);
  __syncthreads();

  for (int kc = kcb; kc < kce; ++kc) {
    int cur = (kc - kcb) & 1;
    const char* pA = ldsc + cur * 65536;
    const char* pB = pA + 32768;
    char* wb = ldsc + (cur ^ 1) * 65536;
    bool pf = (kc + 1 < kce);

    if (pf) ISSUE(gA, i0, kc + 1);
    COMPUTE(0);
    if (pf) {
      WRITEP(wb, gA);
      ISSUE(gB, j0, kc + 1);
    }
    COMPUTE(1);
    if (pf) WRITEP(wb + 32768, gB);
    __syncthreads();
  }

  // epilogue: bf16 partial stores (C/D layout col=lane&15, row=(lane>>4)*4+reg;
  // C symmetric => transpose-robust)
  unsigned short* dst = part + ((size_t)(b * 3 + tile) * NSPLIT + split) * 65536;
  int cn = lane & 15, r0 = (lane >> 4) * 4;
#pragma unroll
  for (int mt = 0; mt < 8; ++mt)
#pragma unroll
    for (int nt = 0; nt < 4; ++nt)
#pragma unroll
      for (int r = 0; r < 4; ++r) {
        int i = wm * 128 + mt * 16 + r0 + r;
        int j = wn * 64 + nt * 16 + cn;
        dst[i * 256 + j] = bfr(acc[mt][nt][r]);
      }
#undef ISSUE
#undef WRITEP
#undef COMPUTE
}

// ---------------------------------------------------------------------------
// reduce: C 256^2 tiles = sum over 40 bf16 partials. 384 blocks x 256 thr.
// ---------------------------------------------------------------------------
__global__ __launch_bounds__(256) void reduce_k(const unsigned short* __restrict__ part,
                                                float* __restrict__ C) {
  int bid = blockIdx.x;             // 0..383
  int inst = bid >> 6;              // 0..5
  int seg = bid & 63;
  int b = inst / 3, tile = inst - (inst / 3) * 3;
  int ti = (tile == 2) ? 1 : 0;
  int tj = (tile == 0) ? 0 : 1;
  const unsigned short* p0 = part + (size_t)inst * NSPLIT * 65536;
  int e = seg * 1024 + threadIdx.x * 4;
  float s0 = 0.f, s1 = 0.f, s2 = 0.f, s3 = 0.f;
#pragma unroll
  for (int sp = 0; sp < NSPLIT; ++sp) {
    ushort4 v = *(const ushort4*)(p0 + (size_t)sp * 65536 + e);
    s0 += __builtin_bit_cast(float, (unsigned int)v.x << 16);
    s1 += __builtin_bit_cast(float, (unsigned int)v.y << 16);
    s2 += __builtin_bit_cast(float, (unsigned int)v.z << 16);
    s3 += __builtin_bit_cast(float, (unsigned int)v.w << 16);
  }
  int r = e >> 8, c = e & 255;
  float4 out = {s0, s1, s2, s3};
  *(float4*)(&C[((size_t)b * 512 + ti * 256 + r) * 512 + tj * 256 + c]) = out;
}

// ---------------------------------------------------------------------------
// mirror: C[b][i][j] = C[b][j][i] for quadrant (1,0): i in [256,512), j in [0,256)
// ---------------------------------------------------------------------------
__global__ __launch_bounds__(256) void mirror_k(float* __restrict__ C) {
  int bid = blockIdx.x;             // 0..31
  int b = bid >> 4, p = bid & 15;
  int I = 4 + (p >> 2), J = p & 3;  // 64-blocks
  __shared__ float tile[64][65];
  int t = threadIdx.x;
  int tx = t & 63, ty = t >> 6;
#pragma unroll
  for (int r = 0; r < 64; r += 4)
    tile[r + ty][tx] = C[((size_t)b * 512 + J * 64 + r + ty) * 512 + I * 64 + tx];
  __syncthreads();
#pragma unroll
  for (int r = 0; r < 64; r += 4)
    C[((size_t)b * 512 + I * 64 + r + ty) * 512 + J * 64 + tx] = tile[tx][r + ty];
}

// ---------------------------------------------------------------------------
// scores + softmax, wave-per-row, 32-row chunks (256 blocks):
// attn[b,h,i,j] = softmax_j( (q'_i.k_j + 0.1*temp_h*hol_ij) * gate[b,j,h] )
// ---------------------------------------------------------------------------
__global__ __launch_bounds__(256) void scores_softmax(
    const float* __restrict__ qkv, const float* __restrict__ gate,
    const float* __restrict__ C, const float* __restrict__ temp,
    float* __restrict__ attn) {
  int bid = blockIdx.x;
  int b = bid >> 7;
  int rem = bid & 127;
  int h = rem >> 4;
  int ic = rem & 15;
  int i0 = ic * 32;

  __shared__ float kh[512][49];
  __shared__ float qs[32][48];
  __shared__ float gs[512];
  __shared__ float sqv[512];

  int t = threadIdx.x;
  const float invF = 1.0f / 147456.0f;
  float ch = 0.1f * temp[h];

  for (int idx = t; idx < 512 * 48; idx += 256) {
    int s = idx / 48, kd = idx - (idx / 48) * 48;
    kh[s][kd] = qkv[(size_t)(b * S + s) * 1152 + 384 + h * 48 + kd];
  }
  for (int idx = t; idx < 32 * 48; idx += 256) {
    int r = idx / 48, kd = idx - (idx / 48) * 48;
    qs[r][kd] = qkv[(size_t)(b * S + i0 + r) * 1152 + h * 48 + kd];
  }
  for (int j = t; j < 512; j += 256) {
    gs[j] = gate[(b * S + j) * 8 + h];
    sqv[j] = C[((size_t)b * S + j) * S + j] * invF;
  }
  __syncthreads();

  int lane = t & 63, wv = t >> 6;
  for (int rr = 0; rr < 8; ++rr) {
    int r = wv * 8 + rr;
    int i = i0 + r;
    const float* Crow = C + ((size_t)b * S + i) * S;
    float sqi = sqv[i];
    float sc[8];
#pragma unroll
    for (int jj = 0; jj < 8; ++jj) {
      int j = jj * 64 + lane;
      float dot = 0.f;
#pragma unroll
      for (int kd = 0; kd < 48; ++kd) dot += qs[r][kd] * kh[j][kd];
      sc[jj] = (dot + ch * (2.0f * Crow[j] * invF - sqi - sqv[j])) * gs[j];
    }
    float m = sc[0];
#pragma unroll
    for (int jj = 1; jj < 8; ++jj) m = fmaxf(m, sc[jj]);
#pragma unroll
    for (int off = 32; off; off >>= 1) m = fmaxf(m, __shfl_xor(m, off));
    float e[8];
    float sum = 0.f;
#pragma unroll
    for (int jj = 0; jj < 8; ++jj) { e[jj] = __expf(sc[jj] - m); sum += e[jj]; }
#pragma unroll
    for (int off = 32; off; off >>= 1) sum += __shfl_xor(sum, off);
    float inv = 1.0f / sum;
    float* arow = attn + (((size_t)(b * 8 + h)) * S + i) * S;
#pragma unroll
    for (int jj = 0; jj < 8; ++jj) arow[jj * 64 + lane] = e[jj] * inv;
  }
}

// ---------------------------------------------------------------------------
// PV: ctx[b,i,h,m] = sum_j attn[b,h,i,j] * v_t[b,j,h,m]. block=(b,h,32 rows)
// ---------------------------------------------------------------------------
__global__ __launch_bounds__(256) void pv_k(const float* __restrict__ attn,
                                            const float* __restrict__ qkv,
                                            float* __restrict__ ctx) {
  int bid = blockIdx.x;
  int b = bid >> 7;
  int rem = bid & 127;
  int h = rem >> 4;
  int ic = rem & 15;
  int i0 = ic * 32;

  __shared__ float vts[64][48];
  __shared__ float ats[32][65];
  int t = threadIdx.x;
  int tx = t & 15, ty = t >> 4;
  int r0 = ty * 2, m0 = tx * 3;
  float acc[2][3] = {};
  for (int jc = 0; jc < 8; ++jc) {
    __syncthreads();
    for (int idx = t; idx < 3072; idx += 256) {
      int jr = idx / 48, m = idx - (idx / 48) * 48;
      vts[jr][m] = qkv[(size_t)(b * S + jc * 64 + jr) * 1152 + 768 + h * 48 + m];
    }
    for (int idx = t; idx < 2048; idx += 256) {
      int r = idx >> 6, j = idx & 63;
      ats[r][j] = attn[(((size_t)(b * 8 + h)) * S + i0 + r) * S + jc * 64 + j];
    }
    __syncthreads();
#pragma unroll 4
    for (int jj = 0; jj < 64; ++jj) {
      float bv0 = vts[jj][m0], bv1 = vts[jj][m0 + 1], bv2 = vts[jj][m0 + 2];
#pragma unroll
      for (int ii = 0; ii < 2; ++ii) {
        float av = ats[r0 + ii][jj];
        acc[ii][0] += av * bv0;
        acc[ii][1] += av * bv1;
        acc[ii][2] += av * bv2;
      }
    }
  }
#pragma unroll
  for (int ii = 0; ii < 2; ++ii)
#pragma unroll
    for (int jm = 0; jm < 3; ++jm)
      ctx[(size_t)(b * S + i0 + r0 + ii) * 384 + h * 48 + m0 + jm] = acc[ii][jm];
}

// ---------------------------------------------------------------------------
extern "C" void kernel_launch(void* const* d_in, const int* in_sizes, int n_in,
                              void* d_out, int out_size, void* d_ws, size_t ws_size,
                              hipStream_t stream) {
  const float* emb  = (const float*)d_in[0];
  const float* curv = (const float*)d_in[1];
  const float* conn = (const float*)d_in[2];
  const float* Wq   = (const float*)d_in[3];
  const float* Wk   = (const float*)d_in[4];
  const float* Wv   = (const float*)d_in[5];
  const float* Wo   = (const float*)d_in[6];
  const float* gk   = (const float*)d_in[7];
  const float* T    = (const float*)d_in[8];
  const float* temp = (const float*)d_in[9];

  float* ws   = (float*)d_ws;
  float* C    = ws;                    // 524288 floats   (2MB)
  float* qkv  = ws + 524288;           // 1179648: [1024][ q' | k | v_t ]
  float* gate = ws + 1703936;          // 8192
  float* Wall = ws + 1712128;          // 442368
  float* ctx  = ws + 2154496;          // 393216
  unsigned short* part = (unsigned short*)(ws + 2547712);  // 15728640 u16 (30MB)
  float* attn = ws + 2547712;          // 4194304 floats, ALIASES part (dead by then)
  // total ws: 10,412,032 floats = 41.6 MB

  prep_wall<<<1728, 256, 0, stream>>>(Wq, Wk, Wv, T, temp, Wall);
  gemm64<<<dim3(18, 16), 256, 0, stream>>>(emb, Wall, qkv, 1024, 1152, 384);
  gate_k<<<32, 256, 0, stream>>>(curv, gk, gate);
  gram_k<<<240, 512, 0, stream>>>(conn, part);
  reduce_k<<<384, 256, 0, stream>>>(part, C);
  mirror_k<<<32, 256, 0, stream>>>(C);
  scores_softmax<<<256, 256, 0, stream>>>(qkv, gate, C, temp, attn);
  pv_k<<<256, 256, 0, stream>>>(attn, qkv, ctx);
  gemm64<<<dim3(6, 16), 256, 0, stream>>>(ctx, Wo, (float*)d_out, 1024, 384, 384);
}